// Round 5
// baseline (1266.314 us; speedup 1.0000x reference)
//
#include <hip/hip_runtime.h>
#include <hip/hip_bf16.h>

typedef __bf16 bf16;
typedef __bf16 bf16x8 __attribute__((ext_vector_type(8)));
typedef __bf16 bf16x4 __attribute__((ext_vector_type(4)));
typedef __bf16 bf16x2 __attribute__((ext_vector_type(2)));
typedef float  f32x4  __attribute__((ext_vector_type(4)));
typedef float  f32x16 __attribute__((ext_vector_type(16)));
typedef unsigned int u32;

#define MFMA(A, B, C)   __builtin_amdgcn_mfma_f32_16x16x32_bf16((A), (B), (C), 0, 0, 0)
#define MFMA32(A, B, C) __builtin_amdgcn_mfma_f32_32x32x16_bf16((A), (B), (C), 0, 0, 0)

static constexpr int BATCH = 4, S = 2048, D = 1024, NH = 16, HD = 64;
static constexpr int M = BATCH * S; // 8192
static constexpr float KL = 0.045084220027780106f; // log2(e)/sqrt(1024)

__device__ __forceinline__ void gload16(const void* g, void* l) {
  __builtin_amdgcn_global_load_lds(
      (const __attribute__((address_space(1))) void*)g,
      (__attribute__((address_space(3))) void*)l, 16, 0, 0);
}

__device__ __forceinline__ float fexp2(float x) {
#if __has_builtin(__builtin_amdgcn_exp2f)
  return __builtin_amdgcn_exp2f(x);
#else
  return exp2f(x);
#endif
}

__device__ __forceinline__ u32 pack2(float a, float b) {
  union { bf16x2 h; u32 u; } c;
  c.h = (bf16x2){(bf16)a, (bf16)b};
  return c.u;
}

union U4 { u32 w[4]; bf16x8 v; };

// counted-vmcnt barrier pair (T4)
#define WAITV_BAR(n)                                        \
  asm volatile("s_waitcnt vmcnt(" #n ")" ::: "memory");     \
  __builtin_amdgcn_s_barrier();                             \
  __builtin_amdgcn_sched_barrier(0);

// ---------------------------------------------------------------------------
// Kernel 1: convert fp32 weights -> bf16, transposed: Wt[n][k] = W[k][n]
// ---------------------------------------------------------------------------
__global__ __launch_bounds__(256) void wt_convert(
    const float* __restrict__ W0, const float* __restrict__ W1,
    const float* __restrict__ W2, const float* __restrict__ W3,
    bf16* __restrict__ WtAll)
{
  const float* W = blockIdx.y == 0 ? W0 : blockIdx.y == 1 ? W1
                 : blockIdx.y == 2 ? W2 : W3;
  bf16* dst = WtAll + (size_t)blockIdx.y * (D * D);
  int k0 = (blockIdx.x >> 4) * 64, n0 = (blockIdx.x & 15) * 64;
  __shared__ __align__(16) bf16 T[64][72];
  int tid = threadIdx.x;
#pragma unroll
  for (int i = 0; i < 4; ++i) {
    int c = tid + i * 256, r = c >> 4, seg = c & 15;
    float4 v = *reinterpret_cast<const float4*>(W + (size_t)(k0 + r) * D + n0 + seg * 4);
    T[seg * 4 + 0][r] = (bf16)v.x; T[seg * 4 + 1][r] = (bf16)v.y;
    T[seg * 4 + 2][r] = (bf16)v.z; T[seg * 4 + 3][r] = (bf16)v.w;
  }
  __syncthreads();
#pragma unroll
  for (int i = 0; i < 2; ++i) {
    int c = tid + i * 256, r = c >> 3, seg = c & 7;
    *reinterpret_cast<bf16x8*>(dst + (size_t)(n0 + r) * D + k0 + seg * 8) =
        *reinterpret_cast<const bf16x8*>(&T[r][seg * 8]);
  }
}

// ---------------------------------------------------------------------------
// Kernel 1b: convert query/key/value fp32 -> bf16 (contiguous Xb, 3 tensors).
// ---------------------------------------------------------------------------
__global__ __launch_bounds__(256) void x_convert(
    const float* __restrict__ X0, const float* __restrict__ X1,
    const float* __restrict__ X2, bf16* __restrict__ Y)
{
  int t = blockIdx.y;
  const float* X = t == 0 ? X0 : t == 1 ? X1 : X2;
  bf16* Yp = Y + (size_t)t * M * D;
  int idx = blockIdx.x * 256 + threadIdx.x;
#pragma unroll
  for (int i = 0; i < 4; ++i) {
    size_t j = (size_t)idx + (size_t)i * 524288;
    float4 v = reinterpret_cast<const float4*>(X)[j];
    bf16x4 o; o[0] = (bf16)v.x; o[1] = (bf16)v.y; o[2] = (bf16)v.z; o[3] = (bf16)v.w;
    reinterpret_cast<bf16x4*>(Yp)[j] = o;
  }
}

// ---------------------------------------------------------------------------
// Kernel 2: QKV projection GEMM. Q output pre-scaled by KL = log2e/sqrt(D).
// grid (512, 3), block 256 = 4 waves. XCD-chunked block swizzle.
// Q/K out: [bh][s][64]; V out transposed: [bh][64][s].
// ---------------------------------------------------------------------------
__global__ __launch_bounds__(256) void qkv_gemm(
    const bf16* __restrict__ Xb, const bf16* __restrict__ WtAll,
    const float* __restrict__ bq, const float* __restrict__ bk, const float* __restrict__ bv,
    bf16* __restrict__ Qb, bf16* __restrict__ Kb, bf16* __restrict__ Vtb)
{
  int v = blockIdx.y;
  const bf16*  X    = Xb + (size_t)v * M * D;
  const bf16*  Wt   = WtAll + (size_t)v * (D * D);
  const float* bias = v == 0 ? bq : v == 1 ? bk : bv;

  int x = blockIdx.x;
  int swz = (x & 7) * 64 + (x >> 3); // XCD-chunked, bijective for 512
  int mt = swz >> 3, nt = swz & 7;
  int m0 = mt * 128, n0 = nt * 128;
  int tid = threadIdx.x, lane = tid & 63, w = tid >> 6;
  int wm = (w >> 1) * 64, wn = (w & 1) * 64;
  int lr = lane & 15, lg = lane >> 4;

  __shared__ __align__(16) unsigned char smem[34816];
  auto As = reinterpret_cast<bf16(*)[128][32]>(smem);          // [2][128][32]
  auto Bs = reinterpret_cast<bf16(*)[128][32]>(smem + 16384);  // [2][128][32]

  f32x4 acc[4][4] = {};

  int srow = w * 32 + (lane >> 2);
  int scol = (lane & 3) * 8;

  auto stage = [&](int buf, int ks) {
    const bf16* ga = X + (size_t)(m0 + srow) * D + ks * 32 + scol;
    bf16* la = &As[buf][w * 32][0];
    gload16(ga, la);
    gload16(ga + 16 * D, la + 16 * 32);
    const bf16* gb = Wt + (size_t)(n0 + srow) * D + ks * 32 + scol;
    bf16* lb = &Bs[buf][w * 32][0];
    gload16(gb, lb);
    gload16(gb + 16 * D, lb + 16 * 32);
  };

  stage(0, 0);
  for (int ks = 0; ks < 32; ++ks) {
    __syncthreads();
    if (ks < 31) stage((ks + 1) & 1, ks + 1);
    int buf = ks & 1;
    bf16x8 af[4], bfr[4];
#pragma unroll
    for (int i = 0; i < 4; ++i)
      af[i] = *reinterpret_cast<const bf16x8*>(&As[buf][wm + i * 16 + lr][8 * lg]);
#pragma unroll
    for (int j = 0; j < 4; ++j)
      bfr[j] = *reinterpret_cast<const bf16x8*>(&Bs[buf][wn + j * 16 + lr][8 * lg]);
#pragma unroll
    for (int i = 0; i < 4; ++i)
#pragma unroll
      for (int j = 0; j < 4; ++j)
        acc[i][j] = MFMA(af[i], bfr[j], acc[i][j]);
  }
  __syncthreads();

  if (v < 2) { // Q/K: LDS [m][n] then coalesced store to [bh][s][64]
    bf16* Out = v == 0 ? Qb : Kb;
    float qs = v == 0 ? KL : 1.0f;
    auto Es = reinterpret_cast<bf16(*)[128]>(smem);
#pragma unroll
    for (int i = 0; i < 4; ++i)
#pragma unroll
      for (int j = 0; j < 4; ++j) {
        int n = wn + j * 16 + lr;
        float bias_n = bias[n0 + n];
#pragma unroll
        for (int r = 0; r < 4; ++r)
          Es[wm + i * 16 + 4 * lg + r][n] = (bf16)((acc[i][j][r] + bias_n) * qs);
      }
    __syncthreads();
#pragma unroll
    for (int i = 0; i < 8; ++i) {
      int c = tid + i * 256, r = c >> 4, seg = c & 15;
      int mg = m0 + r, b = mg >> 11, s = mg & 2047;
      int ng = n0 + seg * 8, h = ng >> 6, d = ng & 63;
      *reinterpret_cast<bf16x8*>(Out + (((size_t)(b * NH + h)) * S + s) * HD + d) =
          *reinterpret_cast<const bf16x8*>(&Es[r][seg * 8]);
    }
  } else { // V: LDS [n][m] (transposed) then coalesced store to [bh][64][s]
    auto Es = reinterpret_cast<bf16(*)[136]>(smem);
#pragma unroll
    for (int i = 0; i < 4; ++i)
#pragma unroll
      for (int j = 0; j < 4; ++j) {
        int n = wn + j * 16 + lr;
        float bias_n = bias[n0 + n];
        bf16x4 t;
#pragma unroll
        for (int r = 0; r < 4; ++r) t[r] = (bf16)(acc[i][j][r] + bias_n);
        *reinterpret_cast<bf16x4*>(&Es[n][wm + i * 16 + 4 * lg]) = t;
      }
    __syncthreads();
#pragma unroll
    for (int i = 0; i < 8; ++i) {
      int c = tid + i * 256, r = c >> 4, seg = c & 15;
      int ng = n0 + r, h = ng >> 6, d = ng & 63;
      int mg = m0 + seg * 8, b = mg >> 11, s = mg & 2047;
      *reinterpret_cast<bf16x8*>(Vtb + (((size_t)(b * NH + h)) * HD + d) * S + s) =
          *reinterpret_cast<const bf16x8*>(&Es[r][seg * 8]);
    }
  }
}

// ---------------------------------------------------------------------------
// Kernel 3: fused attention on 32x32x16 MFMA.
// Block = (b,h) x 64 q-rows. 4 waves: (qh = w&1) q-half, (kh = w>>1) key-half.
// Per tile/wave: QK = 4 MFMA32 (4 LDS b128), PV = 4 MFMA32 (4 LDS b128);
// P->A-frag via packed bf16 + shfl_xor(32) (no LDS round-trip).
// C/D layout 32x32: col=lane&31, row=(reg&3)+8*(reg>>2)+4*(lane>>5).
// A/B frag: row/col=lane&31, k=8*(lane>>5)+i.
// ---------------------------------------------------------------------------
__global__ __launch_bounds__(256) void attn_kernel(
    const bf16* __restrict__ Qb, const bf16* __restrict__ Kb, const bf16* __restrict__ Vtb,
    float* __restrict__ attn_out, bf16* __restrict__ ctx)
{
  int xx = blockIdx.x;
  int xcd = xx & 7, r8 = xx >> 3;
  int bh = xcd + 8 * (r8 >> 5);            // 8 sequential heads per XCD
  int qb = r8 & 31;
  int tid = threadIdx.x, lane = tid & 63, w = tid >> 6;
  int q32 = lane & 31, hi = lane >> 5;
  int qh = w & 1, kh = w >> 1;

  __shared__ __align__(16) bf16 Ks[2][64][64];
  __shared__ __align__(16) bf16 Vs[2][64][64];
  __shared__ float sums[2][64];

  int q_row = qb * 64 + qh * 32 + q32;
  const bf16* Qrow = Qb + ((size_t)bh * S + q_row) * HD;
  bf16x8 qreg[4];
#pragma unroll
  for (int c = 0; c < 4; ++c)
    qreg[c] = *reinterpret_cast<const bf16x8*>(Qrow + c * 16 + 8 * hi);

  // stage 64x64 bf16 tile: linear LDS dest, inverse-swizzled global source
  auto stageK = [&](int buf, int kc) {
    const bf16* base = Kb + ((size_t)bh * S + kc * 64) * HD;
#pragma unroll
    for (int i = 0; i < 2; ++i) {
      int c = i * 256 + tid, row = c >> 3, j = c & 7;
      gload16(base + row * HD + 8 * (j ^ (row & 7)),
              reinterpret_cast<bf16*>(&Ks[buf][0][0]) + c * 8);
    }
  };
  auto stageV = [&](int buf, int kc) {
    const bf16* base = Vtb + (size_t)bh * HD * S + kc * 64;
#pragma unroll
    for (int i = 0; i < 2; ++i) {
      int c = i * 256 + tid, row = c >> 3, j = c & 7;
      gload16(base + (size_t)row * S + 8 * (j ^ (row & 7)),
              reinterpret_cast<bf16*>(&Vs[buf][0][0]) + c * 8);
    }
  };

  int krow = kh * 32 + q32, ks7 = krow & 7;

  // ---- pass A: row sum of exp2(s) over this wave's key-half ----
  float lrun = 0.f;
  stageK(0, 0);
  for (int kc = 0; kc < 32; ++kc) {
    if (kc < 31) {
      stageK((kc + 1) & 1, kc + 1);
      WAITV_BAR(2)
    } else {
      WAITV_BAR(0)
    }
    int buf = kc & 1;
    f32x16 sa = {};
#pragma unroll
    for (int c = 0; c < 4; ++c) {
      bf16x8 kf = *reinterpret_cast<const bf16x8*>(&Ks[buf][krow][8 * ((2 * c + hi) ^ ks7)]);
      sa = MFMA32(kf, qreg[c], sa);
    }
#pragma unroll
    for (int r = 0; r < 16; ++r) lrun += fexp2(sa[r]);
    __builtin_amdgcn_s_barrier();
  }
  lrun += __shfl_xor(lrun, 32);            // combine hi pair (same q)
  if (hi == 0) sums[kh][qh * 32 + q32] = lrun;
  __syncthreads();
  float lg2l = __log2f(sums[0][qh * 32 + q32] + sums[1][qh * 32 + q32]);

  // ---- pass B: recompute, store normalized attn (nt), PV accumulate ----
  f32x16 oaccA = {}, oaccB = {};           // d-halves 0,1 (named: rule #20)
  float* arow = attn_out + ((size_t)bh * S + q_row) * S;

  auto computeB = [&](int buf, int kc) {
    f32x16 sa = {};
#pragma unroll
    for (int c = 0; c < 4; ++c) {
      bf16x8 kf = *reinterpret_cast<const bf16x8*>(&Ks[buf][krow][8 * ((2 * c + hi) ^ ks7)]);
      sa = MFMA32(kf, qreg[c], sa);
    }
    u32 pku[8];
#pragma unroll
    for (int rq = 0; rq < 4; ++rq) {
      f32x4 pv;
#pragma unroll
      for (int j = 0; j < 4; ++j) pv[j] = fexp2(sa[rq * 4 + j] - lg2l);
      __builtin_nontemporal_store(pv,
          reinterpret_cast<f32x4*>(arow + kc * 64 + kh * 32 + 8 * rq + 4 * hi));
      pku[rq * 2 + 0] = pack2(pv[0], pv[1]);
      pku[rq * 2 + 1] = pack2(pv[2], pv[3]);
    }
#pragma unroll
    for (int c2 = 0; c2 < 2; ++c2) {
      // my quad = 2*c2+hi; partner needs it, sends its quad 2*c2+(1-hi)
      u32 myw0 = hi ? pku[4 * c2 + 2] : pku[4 * c2 + 0];
      u32 myw1 = hi ? pku[4 * c2 + 3] : pku[4 * c2 + 1];
      u32 sdw0 = hi ? pku[4 * c2 + 0] : pku[4 * c2 + 2];
      u32 sdw1 = hi ? pku[4 * c2 + 1] : pku[4 * c2 + 3];
      u32 r0 = __shfl_xor(sdw0, 32);
      u32 r1 = __shfl_xor(sdw1, 32);
      U4 f;
      f.w[0] = hi ? r0 : myw0;   // keys %8 in 0..3 (owner hi''=0)
      f.w[1] = hi ? r1 : myw1;
      f.w[2] = hi ? myw0 : r0;   // keys %8 in 4..7 (owner hi''=1)
      f.w[3] = hi ? myw1 : r1;
      {
        int vrow = q32, vs7 = vrow & 7;    // dh = 0
        bf16x8 vf = *reinterpret_cast<const bf16x8*>(
            &Vs[buf][vrow][8 * ((4 * kh + 2 * c2 + hi) ^ vs7)]);
        oaccA = MFMA32(f.v, vf, oaccA);
      }
      {
        int vrow = 32 + q32, vs7 = vrow & 7; // dh = 1
        bf16x8 vf = *reinterpret_cast<const bf16x8*>(
            &Vs[buf][vrow][8 * ((4 * kh + 2 * c2 + hi) ^ vs7)]);
        oaccB = MFMA32(f.v, vf, oaccB);
      }
    }
  };

  // prologue + peeled iter 0 (no stores in flight yet)
  stageK(0, 0); stageV(0, 0);
  stageK(1, 1); stageV(1, 1);
  WAITV_BAR(4)
  computeB(0, 0);
  __builtin_amdgcn_s_barrier();

  for (int kc = 1; kc < 32; ++kc) {
    if (kc < 31) {
      stageK((kc + 1) & 1, kc + 1);
      stageV((kc + 1) & 1, kc + 1);
      WAITV_BAR(8)   // drain 4 oldest = tile-kc loads; stores stay in flight
    } else {
      WAITV_BAR(4)
    }
    computeB(kc & 1, kc);
    __builtin_amdgcn_s_barrier();
  }

  // ---- epilogue: combine kh halves, write ctx ----
  float* fbuf = reinterpret_cast<float*>(&Ks[0][0][0]); // 64x64 f32 = 16 KB
  if (kh == 1) {
#pragma unroll
    for (int reg = 0; reg < 16; ++reg) {
      int qloc = (reg & 3) + 8 * (reg >> 2) + 4 * hi;
      fbuf[(qh * 32 + qloc) * 64 + q32]      = oaccA[reg];
      fbuf[(qh * 32 + qloc) * 64 + 32 + q32] = oaccB[reg];
    }
  }
  __syncthreads();
  bf16* cs = reinterpret_cast<bf16*>(&Vs[0][0][0]); // [64][72] bf16 = 9 KB
  if (kh == 0) {
#pragma unroll
    for (int reg = 0; reg < 16; ++reg) {
      int qloc = (reg & 3) + 8 * (reg >> 2) + 4 * hi;
      cs[(qh * 32 + qloc) * 72 + q32] =
          (bf16)(oaccA[reg] + fbuf[(qh * 32 + qloc) * 64 + q32]);
      cs[(qh * 32 + qloc) * 72 + 32 + q32] =
          (bf16)(oaccB[reg] + fbuf[(qh * 32 + qloc) * 64 + 32 + q32]);
    }
  }
  __syncthreads();
  {
    int b = bh >> 4, h = bh & 15;
    int row = tid >> 2, cseg = (tid & 3) * 16;
    bf16* cp = ctx + ((size_t)b * S + qb * 64 + row) * D + h * HD + cseg;
    *reinterpret_cast<bf16x8*>(cp) =
        *reinterpret_cast<const bf16x8*>(&cs[row * 72 + cseg]);
    *reinterpret_cast<bf16x8*>(cp + 8) =
        *reinterpret_cast<const bf16x8*>(&cs[row * 72 + cseg + 8]);
  }
}

// ---------------------------------------------------------------------------
// Kernel 4: output projection. out(fp32) = ctx(bf16) @ Wo + bo.
// grid (512), block 256. XCD-chunked swizzle.
// ---------------------------------------------------------------------------
__global__ __launch_bounds__(256) void out_gemm(
    const bf16* __restrict__ ctx, const bf16* __restrict__ Wto,
    const float* __restrict__ bo, float* __restrict__ Out)
{
  int x = blockIdx.x;
  int swz = (x & 7) * 64 + (x >> 3);
  int mt = swz >> 3, nt = swz & 7;
  int m0 = mt * 128, n0 = nt * 128;
  int tid = threadIdx.x, lane = tid & 63, w = tid >> 6;
  int wm = (w >> 1) * 64, wn = (w & 1) * 64;
  int lr = lane & 15, lg = lane >> 4;

  __shared__ __align__(16) bf16 As[2][128][32];
  __shared__ __align__(16) bf16 Bs[2][128][32];

  f32x4 acc[4][4] = {};

  int srow = w * 32 + (lane >> 2);
  int scol = (lane & 3) * 8;

  auto stage = [&](int buf, int ks) {
    const bf16* ga = ctx + (size_t)(m0 + srow) * D + ks * 32 + scol;
    bf16* la = &As[buf][w * 32][0];
    gload16(ga, la);
    gload16(ga + 16 * D, la + 16 * 32);
    const bf16* gb = Wto + (size_t)(n0 + srow) * D + ks * 32 + scol;
    bf16* lb = &Bs[buf][w * 32][0];
    gload16(gb, lb);
    gload16(gb + 16 * D, lb + 16 * 32);
  };

  stage(0, 0);
  for (int ks = 0; ks < 32; ++ks) {
    __syncthreads();
    if (ks < 31) stage((ks + 1) & 1, ks + 1);
    int buf = ks & 1;
    bf16x8 af[4], bfr[4];
#pragma unroll
    for (int i = 0; i < 4; ++i)
      af[i] = *reinterpret_cast<const bf16x8*>(&As[buf][wm + i * 16 + lr][8 * lg]);
#pragma unroll
    for (int j = 0; j < 4; ++j)
      bfr[j] = *reinterpret_cast<const bf16x8*>(&Bs[buf][wn + j * 16 + lr][8 * lg]);
#pragma unroll
    for (int i = 0; i < 4; ++i)
#pragma unroll
      for (int j = 0; j < 4; ++j)
        acc[i][j] = MFMA(af[i], bfr[j], acc[i][j]);
  }

#pragma unroll
  for (int i = 0; i < 4; ++i)
#pragma unroll
    for (int j = 0; j < 4; ++j) {
      int n = n0 + wn + j * 16 + lr;
      float bias_n = bo[n];
#pragma unroll
      for (int r = 0; r < 4; ++r)
        Out[(size_t)(m0 + wm + i * 16 + 4 * lg + r) * D + n] = acc[i][j][r] + bias_n;
    }
}

// ---------------------------------------------------------------------------
extern "C" void kernel_launch(void* const* d_in, const int* in_sizes, int n_in,
                              void* d_out, int out_size, void* d_ws, size_t ws_size,
                              hipStream_t stream)
{
  const float* query = (const float*)d_in[0];
  const float* key   = (const float*)d_in[1];
  const float* value = (const float*)d_in[2];
  const float* Wq = (const float*)d_in[3]; const float* bq = (const float*)d_in[4];
  const float* Wk = (const float*)d_in[5]; const float* bk = (const float*)d_in[6];
  const float* Wv = (const float*)d_in[7]; const float* bv = (const float*)d_in[8];
  const float* Wo = (const float*)d_in[9]; const float* bo = (const float*)d_in[10];

  float* out  = (float*)d_out;
  float* attn = out + (size_t)M * D; // 8388608 floats

  char* ws = (char*)d_ws;
  const size_t MiB = 1048576;
  bf16* WtAll = (bf16*)ws;                    // 8 MiB (4 x 1024x1024)
  bf16* Xb    = (bf16*)(ws + 8 * MiB);        // 48 MiB (3 x 8192x1024)
  bf16* Qb    = (bf16*)(ws + 56 * MiB);       // 16 MiB
  bf16* Kb    = (bf16*)(ws + 72 * MiB);       // 16 MiB
  bf16* Vtb   = (bf16*)(ws + 88 * MiB);       // 16 MiB
  bf16* ctx   = Xb;                           // reuse: Xb dead after qkv_gemm

  wt_convert<<<dim3(256, 4), 256, 0, stream>>>(Wq, Wk, Wv, Wo, WtAll);
  x_convert<<<dim3(2048, 3), 256, 0, stream>>>(query, key, value, Xb);
  qkv_gemm<<<dim3(512, 3), 256, 0, stream>>>(Xb, WtAll, bq, bk, bv, Qb, Kb, Vtb);
  attn_kernel<<<dim3(2048), 256, 0, stream>>>(Qb, Kb, Vtb, attn, ctx);
  out_gemm<<<dim3(512), 256, 0, stream>>>(ctx, WtAll + (size_t)3 * D * D, bo, out);
}

// Round 6
// 442.427 us; speedup vs baseline: 2.8622x; 2.8622x over previous
//
#include <hip/hip_runtime.h>
#include <hip/hip_bf16.h>

typedef __bf16 bf16;
typedef __bf16 bf16x8 __attribute__((ext_vector_type(8)));
typedef __bf16 bf16x4 __attribute__((ext_vector_type(4)));
typedef __bf16 bf16x2 __attribute__((ext_vector_type(2)));
typedef float  f32x4  __attribute__((ext_vector_type(4)));
typedef float  f32x16 __attribute__((ext_vector_type(16)));
typedef unsigned int u32;

#define MFMA(A, B, C)   __builtin_amdgcn_mfma_f32_16x16x32_bf16((A), (B), (C), 0, 0, 0)
#define MFMA32(A, B, C) __builtin_amdgcn_mfma_f32_32x32x16_bf16((A), (B), (C), 0, 0, 0)

static constexpr int BATCH = 4, S = 2048, D = 1024, NH = 16, HD = 64;
static constexpr int M = BATCH * S; // 8192
static constexpr float KL = 0.045084220027780106f; // log2(e)/sqrt(1024)

__device__ __forceinline__ void gload16(const void* g, void* l) {
  __builtin_amdgcn_global_load_lds(
      (const __attribute__((address_space(1))) void*)g,
      (__attribute__((address_space(3))) void*)l, 16, 0, 0);
}

__device__ __forceinline__ float fexp2(float x) {
#if __has_builtin(__builtin_amdgcn_exp2f)
  return __builtin_amdgcn_exp2f(x);
#else
  return exp2f(x);
#endif
}

__device__ __forceinline__ u32 pack2(float a, float b) {
  union { bf16x2 h; u32 u; } c;
  c.h = (bf16x2){(bf16)a, (bf16)b};
  return c.u;
}

union U4 { u32 w[4]; bf16x8 v; };

// counted-vmcnt barrier pair (T4)
#define WAITV_BAR(n)                                        \
  asm volatile("s_waitcnt vmcnt(" #n ")" ::: "memory");     \
  __builtin_amdgcn_s_barrier();                             \
  __builtin_amdgcn_sched_barrier(0);

// ---------------------------------------------------------------------------
// Kernel 1: convert fp32 weights -> bf16, transposed: Wt[n][k] = W[k][n]
// ---------------------------------------------------------------------------
__global__ __launch_bounds__(256) void wt_convert(
    const float* __restrict__ W0, const float* __restrict__ W1,
    const float* __restrict__ W2, const float* __restrict__ W3,
    bf16* __restrict__ WtAll)
{
  const float* W = blockIdx.y == 0 ? W0 : blockIdx.y == 1 ? W1
                 : blockIdx.y == 2 ? W2 : W3;
  bf16* dst = WtAll + (size_t)blockIdx.y * (D * D);
  int k0 = (blockIdx.x >> 4) * 64, n0 = (blockIdx.x & 15) * 64;
  __shared__ __align__(16) bf16 T[64][72];
  int tid = threadIdx.x;
#pragma unroll
  for (int i = 0; i < 4; ++i) {
    int c = tid + i * 256, r = c >> 4, seg = c & 15;
    float4 v = *reinterpret_cast<const float4*>(W + (size_t)(k0 + r) * D + n0 + seg * 4);
    T[seg * 4 + 0][r] = (bf16)v.x; T[seg * 4 + 1][r] = (bf16)v.y;
    T[seg * 4 + 2][r] = (bf16)v.z; T[seg * 4 + 3][r] = (bf16)v.w;
  }
  __syncthreads();
#pragma unroll
  for (int i = 0; i < 2; ++i) {
    int c = tid + i * 256, r = c >> 3, seg = c & 7;
    *reinterpret_cast<bf16x8*>(dst + (size_t)(n0 + r) * D + k0 + seg * 8) =
        *reinterpret_cast<const bf16x8*>(&T[r][seg * 8]);
  }
}

// ---------------------------------------------------------------------------
// Kernel 1b: convert query/key/value fp32 -> bf16 (contiguous Xb, 3 tensors).
// ---------------------------------------------------------------------------
__global__ __launch_bounds__(256) void x_convert(
    const float* __restrict__ X0, const float* __restrict__ X1,
    const float* __restrict__ X2, bf16* __restrict__ Y)
{
  int t = blockIdx.y;
  const float* X = t == 0 ? X0 : t == 1 ? X1 : X2;
  bf16* Yp = Y + (size_t)t * M * D;
  int idx = blockIdx.x * 256 + threadIdx.x;
#pragma unroll
  for (int i = 0; i < 4; ++i) {
    size_t j = (size_t)idx + (size_t)i * 524288;
    float4 v = reinterpret_cast<const float4*>(X)[j];
    bf16x4 o; o[0] = (bf16)v.x; o[1] = (bf16)v.y; o[2] = (bf16)v.z; o[3] = (bf16)v.w;
    reinterpret_cast<bf16x4*>(Yp)[j] = o;
  }
}

// ---------------------------------------------------------------------------
// Kernel 2: QKV projection GEMM. Q output pre-scaled by KL = log2e/sqrt(D).
// grid (512, 3), block 256 = 4 waves. XCD-chunked block swizzle.
// Q/K out: [bh][s][64]; V out transposed: [bh][64][s].
// ---------------------------------------------------------------------------
__global__ __launch_bounds__(256) void qkv_gemm(
    const bf16* __restrict__ Xb, const bf16* __restrict__ WtAll,
    const float* __restrict__ bq, const float* __restrict__ bk, const float* __restrict__ bv,
    bf16* __restrict__ Qb, bf16* __restrict__ Kb, bf16* __restrict__ Vtb)
{
  int v = blockIdx.y;
  const bf16*  X    = Xb + (size_t)v * M * D;
  const bf16*  Wt   = WtAll + (size_t)v * (D * D);
  const float* bias = v == 0 ? bq : v == 1 ? bk : bv;

  int x = blockIdx.x;
  int swz = (x & 7) * 64 + (x >> 3); // XCD-chunked, bijective for 512
  int mt = swz >> 3, nt = swz & 7;
  int m0 = mt * 128, n0 = nt * 128;
  int tid = threadIdx.x, lane = tid & 63, w = tid >> 6;
  int wm = (w >> 1) * 64, wn = (w & 1) * 64;
  int lr = lane & 15, lg = lane >> 4;

  __shared__ __align__(16) unsigned char smem[34816];
  auto As = reinterpret_cast<bf16(*)[128][32]>(smem);          // [2][128][32]
  auto Bs = reinterpret_cast<bf16(*)[128][32]>(smem + 16384);  // [2][128][32]

  f32x4 acc[4][4] = {};

  int srow = w * 32 + (lane >> 2);
  int scol = (lane & 3) * 8;

  auto stage = [&](int buf, int ks) {
    const bf16* ga = X + (size_t)(m0 + srow) * D + ks * 32 + scol;
    bf16* la = &As[buf][w * 32][0];
    gload16(ga, la);
    gload16(ga + 16 * D, la + 16 * 32);
    const bf16* gb = Wt + (size_t)(n0 + srow) * D + ks * 32 + scol;
    bf16* lb = &Bs[buf][w * 32][0];
    gload16(gb, lb);
    gload16(gb + 16 * D, lb + 16 * 32);
  };

  stage(0, 0);
  for (int ks = 0; ks < 32; ++ks) {
    __syncthreads();
    if (ks < 31) stage((ks + 1) & 1, ks + 1);
    int buf = ks & 1;
    bf16x8 af[4], bfr[4];
#pragma unroll
    for (int i = 0; i < 4; ++i)
      af[i] = *reinterpret_cast<const bf16x8*>(&As[buf][wm + i * 16 + lr][8 * lg]);
#pragma unroll
    for (int j = 0; j < 4; ++j)
      bfr[j] = *reinterpret_cast<const bf16x8*>(&Bs[buf][wn + j * 16 + lr][8 * lg]);
#pragma unroll
    for (int i = 0; i < 4; ++i)
#pragma unroll
      for (int j = 0; j < 4; ++j)
        acc[i][j] = MFMA(af[i], bfr[j], acc[i][j]);
  }
  __syncthreads();

  if (v < 2) { // Q/K: LDS [m][n] then coalesced store to [bh][s][64]
    bf16* Out = v == 0 ? Qb : Kb;
    float qs = v == 0 ? KL : 1.0f;
    auto Es = reinterpret_cast<bf16(*)[128]>(smem);
#pragma unroll
    for (int i = 0; i < 4; ++i)
#pragma unroll
      for (int j = 0; j < 4; ++j) {
        int n = wn + j * 16 + lr;
        float bias_n = bias[n0 + n];
#pragma unroll
        for (int r = 0; r < 4; ++r)
          Es[wm + i * 16 + 4 * lg + r][n] = (bf16)((acc[i][j][r] + bias_n) * qs);
      }
    __syncthreads();
#pragma unroll
    for (int i = 0; i < 8; ++i) {
      int c = tid + i * 256, r = c >> 4, seg = c & 15;
      int mg = m0 + r, b = mg >> 11, s = mg & 2047;
      int ng = n0 + seg * 8, h = ng >> 6, d = ng & 63;
      *reinterpret_cast<bf16x8*>(Out + (((size_t)(b * NH + h)) * S + s) * HD + d) =
          *reinterpret_cast<const bf16x8*>(&Es[r][seg * 8]);
    }
  } else { // V: LDS [n][m] (transposed) then coalesced store to [bh][64][s]
    auto Es = reinterpret_cast<bf16(*)[136]>(smem);
#pragma unroll
    for (int i = 0; i < 4; ++i)
#pragma unroll
      for (int j = 0; j < 4; ++j) {
        int n = wn + j * 16 + lr;
        float bias_n = bias[n0 + n];
        bf16x4 t;
#pragma unroll
        for (int r = 0; r < 4; ++r) t[r] = (bf16)(acc[i][j][r] + bias_n);
        *reinterpret_cast<bf16x4*>(&Es[n][wm + i * 16 + 4 * lg]) = t;
      }
    __syncthreads();
#pragma unroll
    for (int i = 0; i < 8; ++i) {
      int c = tid + i * 256, r = c >> 4, seg = c & 15;
      int ng = n0 + r, h = ng >> 6, d = ng & 63;
      int mg = m0 + seg * 8, b = mg >> 11, s = mg & 2047;
      *reinterpret_cast<bf16x8*>(Vtb + (((size_t)(b * NH + h)) * HD + d) * S + s) =
          *reinterpret_cast<const bf16x8*>(&Es[r][seg * 8]);
    }
  }
}

// ---------------------------------------------------------------------------
// Kernel 3: fused attention on 32x32x16 MFMA.
// Block = (b,h) x 64 q-rows. 4 waves: (qh = w&1) q-half, (kh = w>>1) key-half.
// P is round-tripped through LDS (Ps f32 [64][68]) so the attn store is a
// separate fully-coalesced phase: each instruction writes 16 full 64B lines.
// PV A-frag via packed bf16 + shfl_xor(32) (unchanged from R5, verified).
// ---------------------------------------------------------------------------
__global__ __launch_bounds__(256) void attn_kernel(
    const bf16* __restrict__ Qb, const bf16* __restrict__ Kb, const bf16* __restrict__ Vtb,
    float* __restrict__ attn_out, bf16* __restrict__ ctx)
{
  int xx = blockIdx.x;
  int xcd = xx & 7, r8 = xx >> 3;
  int bh = xcd + 8 * (r8 >> 5);            // 8 sequential heads per XCD
  int qb = r8 & 31;
  int tid = threadIdx.x, lane = tid & 63, w = tid >> 6;
  int q32 = lane & 31, hi = lane >> 5;
  int qh = w & 1, kh = w >> 1;

  __shared__ __align__(16) bf16 Ks[2][64][64];
  __shared__ __align__(16) bf16 Vs[2][64][64];
  __shared__ __align__(16) float Ps[64][68];   // P tile f32, padded stride
  __shared__ float sums[2][64];

  int q_row = qb * 64 + qh * 32 + q32;
  const bf16* Qrow = Qb + ((size_t)bh * S + q_row) * HD;
  bf16x8 qreg[4];
#pragma unroll
  for (int c = 0; c < 4; ++c)
    qreg[c] = *reinterpret_cast<const bf16x8*>(Qrow + c * 16 + 8 * hi);

  // stage 64x64 bf16 tile: linear LDS dest, inverse-swizzled global source
  auto stageK = [&](int buf, int kc) {
    const bf16* base = Kb + ((size_t)bh * S + kc * 64) * HD;
#pragma unroll
    for (int i = 0; i < 2; ++i) {
      int c = i * 256 + tid, row = c >> 3, j = c & 7;
      gload16(base + row * HD + 8 * (j ^ (row & 7)),
              reinterpret_cast<bf16*>(&Ks[buf][0][0]) + c * 8);
    }
  };
  auto stageV = [&](int buf, int kc) {
    const bf16* base = Vtb + (size_t)bh * HD * S + kc * 64;
#pragma unroll
    for (int i = 0; i < 2; ++i) {
      int c = i * 256 + tid, row = c >> 3, j = c & 7;
      gload16(base + (size_t)row * S + 8 * (j ^ (row & 7)),
              reinterpret_cast<bf16*>(&Vs[buf][0][0]) + c * 8);
    }
  };

  int krow = kh * 32 + q32, ks7 = krow & 7;

  // ---- pass A: row sum of exp2(s) over this wave's key-half ----
  float lrun = 0.f;
  stageK(0, 0);
  for (int kc = 0; kc < 32; ++kc) {
    if (kc < 31) {
      stageK((kc + 1) & 1, kc + 1);
      WAITV_BAR(2)
    } else {
      WAITV_BAR(0)
    }
    int buf = kc & 1;
    f32x16 sa = {};
#pragma unroll
    for (int c = 0; c < 4; ++c) {
      bf16x8 kf = *reinterpret_cast<const bf16x8*>(&Ks[buf][krow][8 * ((2 * c + hi) ^ ks7)]);
      sa = MFMA32(kf, qreg[c], sa);
    }
#pragma unroll
    for (int r = 0; r < 16; ++r) lrun += fexp2(sa[r]);
    __builtin_amdgcn_s_barrier();
  }
  lrun += __shfl_xor(lrun, 32);            // combine hi pair (same q)
  if (hi == 0) sums[kh][qh * 32 + q32] = lrun;
  __syncthreads();
  float lg2l = __log2f(sums[0][qh * 32 + q32] + sums[1][qh * 32 + q32]);

  // ---- pass B: recompute, P -> LDS, PV accumulate; coalesced attn store ----
  f32x16 oaccA = {}, oaccB = {};           // d-halves 0,1 (named: rule #20)
  float* ablk = attn_out + ((size_t)bh * S + qb * 64) * S;

  auto computeB = [&](int buf) {
    f32x16 sa = {};
#pragma unroll
    for (int c = 0; c < 4; ++c) {
      bf16x8 kf = *reinterpret_cast<const bf16x8*>(&Ks[buf][krow][8 * ((2 * c + hi) ^ ks7)]);
      sa = MFMA32(kf, qreg[c], sa);
    }
    u32 pku[8];
#pragma unroll
    for (int rq = 0; rq < 4; ++rq) {
      f32x4 pv;
#pragma unroll
      for (int j = 0; j < 4; ++j) pv[j] = fexp2(sa[rq * 4 + j] - lg2l);
      // P tile LDS write: row = qh*32+q32, col = kh*32 + 8*rq + 4*hi
      *reinterpret_cast<f32x4*>(&Ps[qh * 32 + q32][kh * 32 + 8 * rq + 4 * hi]) = pv;
      pku[rq * 2 + 0] = pack2(pv[0], pv[1]);
      pku[rq * 2 + 1] = pack2(pv[2], pv[3]);
    }
#pragma unroll
    for (int c2 = 0; c2 < 2; ++c2) {
      // my quad = 2*c2+hi; partner needs it, sends its quad 2*c2+(1-hi)
      u32 myw0 = hi ? pku[4 * c2 + 2] : pku[4 * c2 + 0];
      u32 myw1 = hi ? pku[4 * c2 + 3] : pku[4 * c2 + 1];
      u32 sdw0 = hi ? pku[4 * c2 + 0] : pku[4 * c2 + 2];
      u32 sdw1 = hi ? pku[4 * c2 + 1] : pku[4 * c2 + 3];
      u32 r0 = __shfl_xor(sdw0, 32);
      u32 r1 = __shfl_xor(sdw1, 32);
      U4 f;
      f.w[0] = hi ? r0 : myw0;   // keys %8 in 0..3 (owner hi''=0)
      f.w[1] = hi ? r1 : myw1;
      f.w[2] = hi ? myw0 : r0;   // keys %8 in 4..7 (owner hi''=1)
      f.w[3] = hi ? myw1 : r1;
      {
        int vrow = q32, vs7 = vrow & 7;    // dh = 0
        bf16x8 vf = *reinterpret_cast<const bf16x8*>(
            &Vs[buf][vrow][8 * ((4 * kh + 2 * c2 + hi) ^ vs7)]);
        oaccA = MFMA32(f.v, vf, oaccA);
      }
      {
        int vrow = 32 + q32, vs7 = vrow & 7; // dh = 1
        bf16x8 vf = *reinterpret_cast<const bf16x8*>(
            &Vs[buf][vrow][8 * ((4 * kh + 2 * c2 + hi) ^ vs7)]);
        oaccB = MFMA32(f.v, vf, oaccB);
      }
    }
  };

  // coalesced attn store: thread t owns row t>>2; per instr i the 4-lane
  // group writes one full contiguous 64B line (16 full lines / instruction).
  int prow = tid >> 2, pc0 = (tid & 3) * 4;
  auto storeP = [&](int kc) {
    float* dst = ablk + (size_t)prow * S + kc * 64 + pc0;
#pragma unroll
    for (int i = 0; i < 4; ++i)
      __builtin_nontemporal_store(
          *reinterpret_cast<const f32x4*>(&Ps[prow][pc0 + 16 * i]),
          reinterpret_cast<f32x4*>(dst + 16 * i));
  };

  // prologue + peeled iter 0 (no stores in flight yet)
  stageK(0, 0); stageV(0, 0);
  stageK(1, 1); stageV(1, 1);
  WAITV_BAR(4)
  computeB(0);
  __builtin_amdgcn_s_barrier();
  storeP(0);

  for (int kc = 1; kc < 32; ++kc) {
    if (kc < 31) {
      stageK((kc + 1) & 1, kc + 1);
      stageV((kc + 1) & 1, kc + 1);
      // in-order retirement: draining to 8 retires this tile's 4 loads
      // (and any older stores); next-tile loads + newest stores stay out.
      WAITV_BAR(8)
    } else {
      WAITV_BAR(4)
    }
    computeB(kc & 1);
    __builtin_amdgcn_s_barrier();
    storeP(kc);
  }

  // ---- epilogue: combine kh halves, write ctx ----
  float* fbuf = reinterpret_cast<float*>(&Ks[0][0][0]); // 64x64 f32 = 16 KB
  if (kh == 1) {
#pragma unroll
    for (int reg = 0; reg < 16; ++reg) {
      int qloc = (reg & 3) + 8 * (reg >> 2) + 4 * hi;
      fbuf[(qh * 32 + qloc) * 64 + q32]      = oaccA[reg];
      fbuf[(qh * 32 + qloc) * 64 + 32 + q32] = oaccB[reg];
    }
  }
  __syncthreads();
  bf16* cs = reinterpret_cast<bf16*>(&Vs[0][0][0]); // [64][72] bf16 = 9 KB
  if (kh == 0) {
#pragma unroll
    for (int reg = 0; reg < 16; ++reg) {
      int qloc = (reg & 3) + 8 * (reg >> 2) + 4 * hi;
      cs[(qh * 32 + qloc) * 72 + q32] =
          (bf16)(oaccA[reg] + fbuf[(qh * 32 + qloc) * 64 + q32]);
      cs[(qh * 32 + qloc) * 72 + 32 + q32] =
          (bf16)(oaccB[reg] + fbuf[(qh * 32 + qloc) * 64 + 32 + q32]);
    }
  }
  __syncthreads();
  {
    int b = bh >> 4, h = bh & 15;
    int row = tid >> 2, cseg = (tid & 3) * 16;
    bf16* cp = ctx + ((size_t)b * S + qb * 64 + row) * D + h * HD + cseg;
    *reinterpret_cast<bf16x8*>(cp) =
        *reinterpret_cast<const bf16x8*>(&cs[row * 72 + cseg]);
    *reinterpret_cast<bf16x8*>(cp + 8) =
        *reinterpret_cast<const bf16x8*>(&cs[row * 72 + cseg + 8]);
  }
}

// ---------------------------------------------------------------------------
// Kernel 4: output projection. out(fp32) = ctx(bf16) @ Wo + bo.
// grid (512), block 256. XCD-chunked swizzle.
// ---------------------------------------------------------------------------
__global__ __launch_bounds__(256) void out_gemm(
    const bf16* __restrict__ ctx, const bf16* __restrict__ Wto,
    const float* __restrict__ bo, float* __restrict__ Out)
{
  int x = blockIdx.x;
  int swz = (x & 7) * 64 + (x >> 3);
  int mt = swz >> 3, nt = swz & 7;
  int m0 = mt * 128, n0 = nt * 128;
  int tid = threadIdx.x, lane = tid & 63, w = tid >> 6;
  int wm = (w >> 1) * 64, wn = (w & 1) * 64;
  int lr = lane & 15, lg = lane >> 4;

  __shared__ __align__(16) bf16 As[2][128][32];
  __shared__ __align__(16) bf16 Bs[2][128][32];

  f32x4 acc[4][4] = {};

  int srow = w * 32 + (lane >> 2);
  int scol = (lane & 3) * 8;

  auto stage = [&](int buf, int ks) {
    const bf16* ga = ctx + (size_t)(m0 + srow) * D + ks * 32 + scol;
    bf16* la = &As[buf][w * 32][0];
    gload16(ga, la);
    gload16(ga + 16 * D, la + 16 * 32);
    const bf16* gb = Wto + (size_t)(n0 + srow) * D + ks * 32 + scol;
    bf16* lb = &Bs[buf][w * 32][0];
    gload16(gb, lb);
    gload16(gb + 16 * D, lb + 16 * 32);
  };

  stage(0, 0);
  for (int ks = 0; ks < 32; ++ks) {
    __syncthreads();
    if (ks < 31) stage((ks + 1) & 1, ks + 1);
    int buf = ks & 1;
    bf16x8 af[4], bfr[4];
#pragma unroll
    for (int i = 0; i < 4; ++i)
      af[i] = *reinterpret_cast<const bf16x8*>(&As[buf][wm + i * 16 + lr][8 * lg]);
#pragma unroll
    for (int j = 0; j < 4; ++j)
      bfr[j] = *reinterpret_cast<const bf16x8*>(&Bs[buf][wn + j * 16 + lr][8 * lg]);
#pragma unroll
    for (int i = 0; i < 4; ++i)
#pragma unroll
      for (int j = 0; j < 4; ++j)
        acc[i][j] = MFMA(af[i], bfr[j], acc[i][j]);
  }

#pragma unroll
  for (int i = 0; i < 4; ++i)
#pragma unroll
    for (int j = 0; j < 4; ++j) {
      int n = n0 + wn + j * 16 + lr;
      float bias_n = bo[n];
#pragma unroll
      for (int r = 0; r < 4; ++r)
        Out[(size_t)(m0 + wm + i * 16 + 4 * lg + r) * D + n] = acc[i][j][r] + bias_n;
    }
}

// ---------------------------------------------------------------------------
extern "C" void kernel_launch(void* const* d_in, const int* in_sizes, int n_in,
                              void* d_out, int out_size, void* d_ws, size_t ws_size,
                              hipStream_t stream)
{
  const float* query = (const float*)d_in[0];
  const float* key   = (const float*)d_in[1];
  const float* value = (const float*)d_in[2];
  const float* Wq = (const float*)d_in[3]; const float* bq = (const float*)d_in[4];
  const float* Wk = (const float*)d_in[5]; const float* bk = (const float*)d_in[6];
  const float* Wv = (const float*)d_in[7]; const float* bv = (const float*)d_in[8];
  const float* Wo = (const float*)d_in[9]; const float* bo = (const float*)d_in[10];

  float* out  = (float*)d_out;
  float* attn = out + (size_t)M * D; // 8388608 floats

  char* ws = (char*)d_ws;
  const size_t MiB = 1048576;
  bf16* WtAll = (bf16*)ws;                    // 8 MiB (4 x 1024x1024)
  bf16* Xb    = (bf16*)(ws + 8 * MiB);        // 48 MiB (3 x 8192x1024)
  bf16* Qb    = (bf16*)(ws + 56 * MiB);       // 16 MiB
  bf16* Kb    = (bf16*)(ws + 72 * MiB);       // 16 MiB
  bf16* Vtb   = (bf16*)(ws + 88 * MiB);       // 16 MiB
  bf16* ctx   = Xb;                           // reuse: Xb dead after qkv_gemm

  wt_convert<<<dim3(256, 4), 256, 0, stream>>>(Wq, Wk, Wv, Wo, WtAll);
  x_convert<<<dim3(2048, 3), 256, 0, stream>>>(query, key, value, Xb);
  qkv_gemm<<<dim3(512, 3), 256, 0, stream>>>(Xb, WtAll, bq, bk, bv, Qb, Kb, Vtb);
  attn_kernel<<<dim3(2048), 256, 0, stream>>>(Qb, Kb, Vtb, attn, ctx);
  out_gemm<<<dim3(512), 256, 0, stream>>>(ctx, WtAll + (size_t)3 * D * D, bo, out);
}